// Round 7
// baseline (263.696 us; speedup 1.0000x reference)
//
#include <hip/hip_runtime.h>
#include <hip/hip_bf16.h>
#include <math.h>

#define NN   8192
#define EE   262144
#define CC   256
#define HH   4

typedef __bf16 bf16;
typedef __bf16 bf16x8 __attribute__((ext_vector_type(8)));
typedef __bf16 bf16x4 __attribute__((ext_vector_type(4)));
typedef __bf16 bf16x2 __attribute__((ext_vector_type(2)));
typedef float  f32x4  __attribute__((ext_vector_type(4)));

static __device__ __forceinline__ bf16 f2bf(float f) { return (bf16)f; }

// packed f32x2 -> bf16x2 in one dword (v_cvt_pk_bf16_f32)
static __device__ __forceinline__ unsigned pk2(float a, float b) {
    __hip_bfloat162 h = __float22bfloat162_rn(float2{a, b});
    return *reinterpret_cast<unsigned*>(&h);
}

// ---------------------------------------------------------------- fused prep
__global__ void prep_all(const float* __restrict__ x, bf16* __restrict__ xb,
                         const float* __restrict__ ipw, const float* __restrict__ opw,
                         const float* __restrict__ fcw, const float* __restrict__ wloc,
                         bf16* __restrict__ ipwb, bf16* __restrict__ opwb,
                         bf16* __restrict__ fcwb, bf16* __restrict__ wlTb,
                         const int* __restrict__ adj, int* __restrict__ ideg) {
    int b = blockIdx.x, t = threadIdx.x;
    if (b < 2048) {
        for (int i = b * 256 + t; i < NN * CC; i += 2048 * 256) xb[i] = f2bf(x[i]);
    } else if (b < 2816) { int i = (b - 2048) * 256 + t; ipwb[i] = f2bf(ipw[i]); }
    else if (b < 3072)   { int i = (b - 2816) * 256 + t; opwb[i] = f2bf(opw[i]); }
    else if (b < 3328)   { int i = (b - 3072) * 256 + t; fcwb[i] = f2bf(fcw[i]); }
    else if (b < 3584)   { int n = b - 3328;             wlTb[n * 256 + t] = f2bf(wloc[t * 256 + n]); }
    else {
        int e = (b - 3584) * 256 + t;
        if (e < EE) atomicAdd(&ideg[adj[EE + e]], 1);
    }
}

// ---------------------------------------------------------------- K/V fragment prepack (fused)
__global__ __launch_bounds__(256) void build_kv(const bf16* __restrict__ qkv,
                                                bf16* __restrict__ Kpk,
                                                bf16* __restrict__ Vpk) {
    __shared__ bf16 tl[64][72];
    const int bx = blockIdx.x;     // 64-key tile
    const int h  = blockIdx.y;
    const int tid = threadIdx.x;
    // ---- K
    #pragma unroll
    for (int i = 0; i < 2; i++) {
        int u = tid + i * 256;
        int key = u >> 3, g = u & 7;
        *reinterpret_cast<bf16x8*>(&tl[key][g * 8]) =
            *reinterpret_cast<const bf16x8*>(qkv + (size_t)(bx * 64 + key) * 768 + 256 + h * 64 + g * 8);
    }
    __syncthreads();
    #pragma unroll
    for (int i = 0; i < 2; i++) {
        int ee = tid + i * 256;
        int l15 = ee & 15, quad = (ee >> 4) & 3, c = (ee >> 6) & 1, ktl = ee >> 7;
        int key_local = (ktl >> 1) * 32 + (l15 >> 2) * 8 + (ktl & 1) * 4 + (l15 & 3);
        bf16x8 v = *reinterpret_cast<const bf16x8*>(&tl[key_local][c * 32 + quad * 8]);
        *reinterpret_cast<bf16x8*>(Kpk + ((size_t)((h * 512 + bx * 4 + ktl) * 2 + c)) * 512
                                       + (quad * 16 + l15) * 8) = v;
    }
    __syncthreads();
    // ---- V
    #pragma unroll
    for (int i = 0; i < 2; i++) {
        int u = tid + i * 256;
        int key = u >> 3, g = u & 7;
        *reinterpret_cast<bf16x8*>(&tl[key][g * 8]) =
            *reinterpret_cast<const bf16x8*>(qkv + (size_t)(bx * 64 + key) * 768 + 512 + h * 64 + g * 8);
    }
    __syncthreads();
    #pragma unroll
    for (int i = 0; i < 2; i++) {
        int ee = tid + i * 256;
        int l15 = ee & 15, quad = (ee >> 4) & 3, nt = (ee >> 6) & 3, kcl = ee >> 8;
        bf16x8 v;
        #pragma unroll
        for (int j = 0; j < 8; j++) v[j] = tl[kcl * 32 + quad * 8 + j][nt * 16 + l15];
        *reinterpret_cast<bf16x8*>(Vpk + ((size_t)((h * 256 + bx * 2 + kcl) * 4 + nt)) * 512
                                       + (quad * 16 + l15) * 8) = v;
    }
}

// ---------------------------------------------------------------- GCN CSR build
__global__ __launch_bounds__(256) void scan_offsets(const int* __restrict__ ideg,
        int* __restrict__ off, int* __restrict__ cursor, float* __restrict__ rs) {
    __shared__ int ps[256];
    const int tid = threadIdx.x;
    const int base = tid * 32;
    int loc[32];
    int s = 0;
    #pragma unroll
    for (int i = 0; i < 32; i++) { loc[i] = s; s += ideg[base + i]; }
    ps[tid] = s;
    __syncthreads();
    for (int d = 1; d < 256; d <<= 1) {
        int v = (tid >= d) ? ps[tid - d] : 0;
        __syncthreads();
        ps[tid] += v;
        __syncthreads();
    }
    int excl = ps[tid] - s;
    #pragma unroll
    for (int i = 0; i < 32; i++) {
        int o = excl + loc[i];
        off[base + i] = o;
        cursor[base + i] = o;
        int dg = ideg[base + i];
        rs[base + i] = dg > 0 ? rsqrtf((float)dg) : 0.f;
    }
    if (tid == 255) off[8192] = excl + s;
}

__global__ void fill_csr(const int* __restrict__ adj, int* __restrict__ cursor,
                         int* __restrict__ csr) {
    int e = blockIdx.x * 256 + threadIdx.x;
    if (e < EE) {
        int col = adj[EE + e];
        int pos = atomicAdd(&cursor[col], 1);
        csr[pos] = adj[e];
    }
}

// ---------------------------------------------------------------- GCN gather v3
__global__ __launch_bounds__(256) void gcn_gather3(const bf16* __restrict__ xb,
        const int* __restrict__ csr, const int* __restrict__ off,
        const float* __restrict__ rs, bf16* __restrict__ hib) {
    const int node = blockIdx.x * 2 + (threadIdx.x >> 7);
    const int j = threadIdx.x & 127;
    const int o = off[node];
    const int cnt = off[node + 1] - o;
    const float rsc = rs[node];
    const unsigned* xrow = (const unsigned*)xb;
    float a0 = 0.f, a1 = 0.f;
    int e = 0;
    for (; e + 8 <= cnt; e += 8) {
        int r[8];
        float v[8];
        unsigned u[8];
        #pragma unroll
        for (int i = 0; i < 8; i++) r[i] = csr[o + e + i];
        #pragma unroll
        for (int i = 0; i < 8; i++) v[i] = rsc * rs[r[i]];
        #pragma unroll
        for (int i = 0; i < 8; i++) u[i] = xrow[(size_t)r[i] * 128 + j];
        #pragma unroll
        for (int i = 0; i < 8; i++) {
            a0 += __uint_as_float(u[i] << 16) * v[i];
            a1 += __uint_as_float(u[i] & 0xffff0000u) * v[i];
        }
    }
    for (; e < cnt; e++) {
        int r0 = csr[o + e];
        float v0 = rsc * rs[r0];
        unsigned u0 = xrow[(size_t)r0 * 128 + j];
        a0 += __uint_as_float(u0 << 16) * v0;
        a1 += __uint_as_float(u0 & 0xffff0000u) * v0;
    }
    bf16x2 pk;
    pk[0] = f2bf(a0);
    pk[1] = f2bf(a1);
    ((bf16x2*)(hib + (size_t)node * CC))[j] = pk;
}

// ---------------------------------------------------------------- BT GEMM (qkv)
__global__ __launch_bounds__(256) void gemm_bt(
        const bf16* __restrict__ A, const bf16* __restrict__ W,
        const float* __restrict__ bias,
        float* __restrict__ outF, bf16* __restrict__ outB,
        int M, int N, int K) {
    const int tid  = threadIdx.x;
    const int wave = tid >> 6;
    const int lane = tid & 63;
    const int quad = lane >> 4;
    const int l15  = lane & 15;
    const int m0 = blockIdx.x * 128;
    const int n0 = blockIdx.y * 64;

    __shared__ bf16 Alds[128][72];
    __shared__ bf16 Wlds[64][72];

    f32x4 acc[2][4];
    #pragma unroll
    for (int mt = 0; mt < 2; mt++)
        #pragma unroll
        for (int nt = 0; nt < 4; nt++)
            acc[mt][nt] = (f32x4){0.f, 0.f, 0.f, 0.f};

    for (int k0 = 0; k0 < K; k0 += 64) {
        #pragma unroll
        for (int i = 0; i < 4; i++) {
            int u = tid + i * 256;
            int r = u >> 3;
            int cp = u & 7;
            *reinterpret_cast<bf16x8*>(&Alds[r][cp * 8]) =
                *reinterpret_cast<const bf16x8*>(A + (size_t)(m0 + r) * K + k0 + cp * 8);
        }
        #pragma unroll
        for (int i = 0; i < 2; i++) {
            int u = tid + i * 256;
            int r = u >> 3;
            int cp = u & 7;
            *reinterpret_cast<bf16x8*>(&Wlds[r][cp * 8]) =
                *reinterpret_cast<const bf16x8*>(W + (size_t)(n0 + r) * K + k0 + cp * 8);
        }
        __syncthreads();
        #pragma unroll
        for (int c = 0; c < 2; c++) {
            bf16x8 af[2], wf[4];
            #pragma unroll
            for (int mt = 0; mt < 2; mt++)
                af[mt] = *reinterpret_cast<const bf16x8*>(&Alds[wave * 32 + mt * 16 + l15][c * 32 + quad * 8]);
            #pragma unroll
            for (int nt = 0; nt < 4; nt++)
                wf[nt] = *reinterpret_cast<const bf16x8*>(&Wlds[nt * 16 + l15][c * 32 + quad * 8]);
            #pragma unroll
            for (int mt = 0; mt < 2; mt++)
                #pragma unroll
                for (int nt = 0; nt < 4; nt++)
                    acc[mt][nt] = __builtin_amdgcn_mfma_f32_16x16x32_bf16(af[mt], wf[nt], acc[mt][nt], 0, 0, 0);
        }
        __syncthreads();
    }
    #pragma unroll
    for (int mt = 0; mt < 2; mt++)
        #pragma unroll
        for (int nt = 0; nt < 4; nt++)
            #pragma unroll
            for (int r = 0; r < 4; r++) {
                int m = m0 + wave * 32 + mt * 16 + quad * 4 + r;
                int n = n0 + nt * 16 + l15;
                float v = acc[mt][nt][r];
                if (bias) v += bias[n];
                if (outF) outF[(size_t)m * N + n] = v;
                else      outB[(size_t)m * N + n] = f2bf(v);
            }
}

// ---------------------------------------------------------------- flash attention v17
// v14's split-K geometry WITHOUT the register squeeze. v14 failed solely
// from __launch_bounds__(512,4): VGPR capped at 64 -> 2.2 GB spill
// (WRITE_SIZE). Here (512,2): compiler keeps ~124 VGPR; 4 waves/SIMD come
// from TWO independently-started blocks (124x4=496<=512 VGPR, 2x70KB=140KB
// LDS). Staggered block starts break the phase-lock that made MFMA and
// VALU serialize (v10-v16: MfmaUtil+VALUBusy ~ 97%, elapsed ~ sum of
// pipes). Target: elapsed -> max(MFMA 34us, VALU 42us) ~ 45-55us.
// Exact split-K: m=0 softmax partials are pure sums; blocks write f32
// partial O + l, combine_attn merges.
__global__ __launch_bounds__(512, 2) void flash_attn17(const bf16* __restrict__ qkv,
                                                       const bf16* __restrict__ Kpk,
                                                       const bf16* __restrict__ Vpk,
                                                       float* __restrict__ Opf,
                                                       float* __restrict__ lpf) {
    const int tid  = threadIdx.x;
    const int w    = tid >> 6;           // 0..7
    const int g    = w >> 2;             // q-group
    const int k4   = w & 3;              // key-split lane within group
    const int lane = tid & 63;
    const int quad = lane >> 4;
    const int l15  = lane & 15;
    const int bx = blockIdx.x;
    const int h  = bx & 3;
    const int qb = (bx >> 2) & 63;       // q-tile (128 q)
    const int kh = bx >> 8;              // key half (0/1)
    const int qbase = qb * 128 + g * 64;
    const int cb = kh * 128;             // chunk base (32-key chunks, 256/head)

    __shared__ bf16 Osh[8][64][68];
    __shared__ float lsh[8][64];

    const float qs = 0.180336880f;
    bf16x8 qf[4][2];
    #pragma unroll
    for (int qt = 0; qt < 4; qt++)
        #pragma unroll
        for (int c = 0; c < 2; c++) {
            bf16x8 raw = *reinterpret_cast<const bf16x8*>(
                qkv + (size_t)(qbase + qt * 16 + l15) * 768 + h * 64 + c * 32 + quad * 8);
            #pragma unroll
            for (int j = 0; j < 8; j++) qf[qt][c][j] = f2bf((float)raw[j] * qs);
        }

    const bf16* Kb = Kpk + (size_t)h * 524288 + lane * 8;
    const bf16* Vb = Vpk + (size_t)h * 524288 + lane * 8;

    f32x4 oacc[4][4];
    #pragma unroll
    for (int qt = 0; qt < 4; qt++)
        #pragma unroll
        for (int nt = 0; nt < 4; nt++) oacc[qt][nt] = (f32x4){0.f, 0.f, 0.f, 0.f};
    f32x4 lacc[4];
    #pragma unroll
    for (int qt = 0; qt < 4; qt++) lacc[qt] = (f32x4){0.f, 0.f, 0.f, 0.f};
    bf16x8 onesf;
    #pragma unroll
    for (int j = 0; j < 8; j++) onesf[j] = f2bf(1.0f);
    const f32x4 z4 = (f32x4){0.f, 0.f, 0.f, 0.f};

    bf16x8 kfA[2][2], vfA[4], kfB[2][2], vfB[4];

    #define LOADKV(kc, kf, vf)                                                          \
        {                                                                               \
            _Pragma("unroll")                                                           \
            for (int s = 0; s < 2; s++)                                                 \
                _Pragma("unroll")                                                       \
                for (int c = 0; c < 2; c++)                                             \
                    kf[s][c] = *reinterpret_cast<const bf16x8*>(Kb + (size_t)(kc) * 2048 + s * 1024 + c * 512); \
            _Pragma("unroll")                                                           \
            for (int nt = 0; nt < 4; nt++)                                              \
                vf[nt] = *reinterpret_cast<const bf16x8*>(Vb + (size_t)(kc) * 2048 + nt * 512); \
        }

    #define COMPUTE(kf, vf)                                                             \
        {                                                                               \
            f32x4 sacc[2][4];                                                           \
            __builtin_amdgcn_s_setprio(1);                                              \
            _Pragma("unroll")                                                           \
            for (int s = 0; s < 2; s++)                                                 \
                _Pragma("unroll")                                                       \
                for (int qt = 0; qt < 4; qt++) {                                        \
                    sacc[s][qt] = __builtin_amdgcn_mfma_f32_16x16x32_bf16(kf[s][0], qf[qt][0], z4, 0, 0, 0); \
                    sacc[s][qt] = __builtin_amdgcn_mfma_f32_16x16x32_bf16(kf[s][1], qf[qt][1], sacc[s][qt], 0, 0, 0); \
                }                                                                       \
            __builtin_amdgcn_s_setprio(0);                                              \
            _Pragma("unroll")                                                           \
            for (int qt = 0; qt < 4; qt++) {                                            \
                float e0 = __builtin_amdgcn_exp2f(sacc[0][qt][0]);                      \
                float e1 = __builtin_amdgcn_exp2f(sacc[0][qt][1]);                      \
                float e2 = __builtin_amdgcn_exp2f(sacc[0][qt][2]);                      \
                float e3 = __builtin_amdgcn_exp2f(sacc[0][qt][3]);                      \
                float e4 = __builtin_amdgcn_exp2f(sacc[1][qt][0]);                      \
                float e5 = __builtin_amdgcn_exp2f(sacc[1][qt][1]);                      \
                float e6 = __builtin_amdgcn_exp2f(sacc[1][qt][2]);                      \
                float e7 = __builtin_amdgcn_exp2f(sacc[1][qt][3]);                      \
                union { bf16x8 v; unsigned u[4]; } pu;                                  \
                pu.u[0] = pk2(e0, e1);                                                  \
                pu.u[1] = pk2(e2, e3);                                                  \
                pu.u[2] = pk2(e4, e5);                                                  \
                pu.u[3] = pk2(e6, e7);                                                  \
                __builtin_amdgcn_s_setprio(1);                                          \
                _Pragma("unroll")                                                       \
                for (int nt = 0; nt < 4; nt++)                                          \
                    oacc[qt][nt] = __builtin_amdgcn_mfma_f32_16x16x32_bf16(pu.v, vf[nt], oacc[qt][nt], 0, 0, 0); \
                lacc[qt] = __builtin_amdgcn_mfma_f32_16x16x32_bf16(pu.v, onesf, lacc[qt], 0, 0, 0); \
                __builtin_amdgcn_s_setprio(0);                                          \
            }                                                                           \
        }

    LOADKV(cb + k4, kfA, vfA);
    for (int it = 0; it < 32; it += 2) {
        const int kB = cb + k4 + (it + 1) * 4;
        LOADKV(kB, kfB, vfB);
        COMPUTE(kfA, vfA);
        int kA2 = cb + k4 + (it + 2) * 4;
        if (it + 2 >= 32) kA2 = cb + k4;   // harmless wrap reload on final trip
        LOADKV(kA2, kfA, vfA);
        COMPUTE(kfB, vfB);
    }
    #undef LOADKV
    #undef COMPUTE

    #pragma unroll
    for (int qt = 0; qt < 4; qt++)
        #pragma unroll
        for (int nt = 0; nt < 4; nt++)
            #pragma unroll
            for (int r = 0; r < 4; r++)
                Osh[w][qt * 16 + quad * 4 + r][nt * 16 + l15] = f2bf(oacc[qt][nt][r]);
    if (l15 == 0) {
        #pragma unroll
        for (int qt = 0; qt < 4; qt++)
            #pragma unroll
            for (int r = 0; r < 4; r++)
                lsh[w][qt * 16 + quad * 4 + r] = lacc[qt][r];
    }
    __syncthreads();

    // reduce 4 key-split partials; write f32 partial O + l (no division)
    const int q7 = tid >> 2;             // 0..127
    const int gg = q7 >> 6;
    const int ql = q7 & 63;
    const int ds = (tid & 3) * 16;
    const int wb = gg * 4;
    float lsum = lsh[wb][ql] + lsh[wb + 1][ql] + lsh[wb + 2][ql] + lsh[wb + 3][ql];
    float acc[16];
    #pragma unroll
    for (int i = 0; i < 16; i++) acc[i] = 0.f;
    #pragma unroll
    for (int v = 0; v < 4; v++) {
        bf16x8 o0 = *reinterpret_cast<const bf16x8*>(&Osh[wb + v][ql][ds]);
        bf16x8 o1 = *reinterpret_cast<const bf16x8*>(&Osh[wb + v][ql][ds + 8]);
        #pragma unroll
        for (int i = 0; i < 8; i++) { acc[i] += (float)o0[i]; acc[8 + i] += (float)o1[i]; }
    }
    float* od = Opf + (size_t)bx * 8192 + q7 * 64 + ds;
    #pragma unroll
    for (int p4 = 0; p4 < 4; p4++) {
        f32x4 v4 = (f32x4){acc[p4 * 4], acc[p4 * 4 + 1], acc[p4 * 4 + 2], acc[p4 * 4 + 3]};
        *reinterpret_cast<f32x4*>(od + p4 * 4) = v4;
    }
    if ((tid & 3) == 0) lpf[bx * 128 + q7] = lsum;
}

// ---------------------------------------------------------------- split-K combine
__global__ __launch_bounds__(256) void combine_attn(const float* __restrict__ Opf,
                                                    const float* __restrict__ lpf,
                                                    bf16* __restrict__ attnO) {
    const int gid = blockIdx.x * 256 + threadIdx.x;  // 0..524287
    const int d   = (gid & 15) * 4;
    const int q7  = (gid >> 4) & 127;
    const int rest = gid >> 11;                      // 0..255
    const int h  = rest & 3;
    const int qb = rest >> 2;
    const int sA = qb * 4 + h;
    const int sB = sA + 256;
    const float la = lpf[sA * 128 + q7];
    const float lb = lpf[sB * 128 + q7];
    const float linv = 1.f / (la + lb);
    f32x4 oa = *reinterpret_cast<const f32x4*>(Opf + (size_t)sA * 8192 + q7 * 64 + d);
    f32x4 ob = *reinterpret_cast<const f32x4*>(Opf + (size_t)sB * 8192 + q7 * 64 + d);
    bf16x4 r;
    #pragma unroll
    for (int i = 0; i < 4; i++) r[i] = f2bf((oa[i] + ob[i]) * linv);
    *reinterpret_cast<bf16x4*>(attnO + (size_t)(qb * 128 + q7) * CC + h * 64 + d) = r;
}

// ---------------------------------------------------------------- gemm + LN + combine + fc
__global__ __launch_bounds__(256) void gemm_ln_fc(
        const bf16* __restrict__ aOb, const bf16* __restrict__ opwb, const float* __restrict__ opb,
        const bf16* __restrict__ hib, const bf16* __restrict__ wlTb,
        const float* __restrict__ x, const float* __restrict__ lng, const float* __restrict__ lnb,
        const float* __restrict__ alp, const bf16* __restrict__ fcwb, const float* __restrict__ fcb,
        float* __restrict__ out) {
    const int tid = threadIdx.x;
    const int w = tid >> 6, lane = tid & 63, quad = lane >> 4, l15 = lane & 15;
    const int m0 = blockIdx.x * 16;
    const int n0w = w * 64;
    const f32x4 z4 = (f32x4){0.f, 0.f, 0.f, 0.f};

    __shared__ bf16 Ab[16][264];
    __shared__ float Xl[16][260];
    __shared__ float rsum[4][16], rsq[4][16];

    #pragma unroll
    for (int i = 0; i < 4; i++) {
        int u = tid + i * 256;
        int row = u >> 6, cp = (u & 63) * 4;
        *reinterpret_cast<f32x4*>(&Xl[row][cp]) =
            *reinterpret_cast<const f32x4*>(x + (size_t)(m0 + row) * CC + cp);
    }

    // ---- gemm0: aprj tile (A = aOb)
    #pragma unroll
    for (int i = 0; i < 2; i++) {
        int u = tid + i * 256;
        int row = u >> 5, cp = (u & 31) * 8;
        *reinterpret_cast<bf16x8*>(&Ab[row][cp]) =
            *reinterpret_cast<const bf16x8*>(aOb + (size_t)(m0 + row) * CC + cp);
    }
    __syncthreads();
    f32x4 r0[4], r1[4], acc[4];
    #pragma unroll
    for (int nt = 0; nt < 4; nt++) acc[nt] = z4;
    for (int kc = 0; kc < 4; kc++)
        #pragma unroll
        for (int c = 0; c < 2; c++) {
            bf16x8 af = *reinterpret_cast<const bf16x8*>(&Ab[l15][kc * 64 + c * 32 + quad * 8]);
            #pragma unroll
            for (int nt = 0; nt < 4; nt++) {
                bf16x8 wf = *reinterpret_cast<const bf16x8*>(
                    opwb + (size_t)(n0w + nt * 16 + l15) * CC + kc * 64 + c * 32 + quad * 8);
                acc[nt] = __builtin_amdgcn_mfma_f32_16x16x32_bf16(af, wf, acc[nt], 0, 0, 0);
            }
        }
    #pragma unroll
    for (int nt = 0; nt < 4; nt++) r0[nt] = acc[nt];
    __syncthreads();

    // ---- gemm1: locl tile (A = hib)
    #pragma unroll
    for (int i = 0; i < 2; i++) {
        int u = tid + i * 256;
        int row = u >> 5, cp = (u & 31) * 8;
        *reinterpret_cast<bf16x8*>(&Ab[row][cp]) =
            *reinterpret_cast<const bf16x8*>(hib + (size_t)(m0 + row) * CC + cp);
    }
    __syncthreads();
    #pragma unroll
    for (int nt = 0; nt < 4; nt++) acc[nt] = z4;
    for (int kc = 0; kc < 4; kc++)
        #pragma unroll
        for (int c = 0; c < 2; c++) {
            bf16x8 af = *reinterpret_cast<const bf16x8*>(&Ab[l15][kc * 64 + c * 32 + quad * 8]);
            #pragma unroll
            for (int nt = 0; nt < 4; nt++) {
                bf16x8 wf = *reinterpret_cast<const bf16x8*>(
                    wlTb + (size_t)(n0w + nt * 16 + l15) * CC + kc * 64 + c * 32 + quad * 8);
                acc[nt] = __builtin_amdgcn_mfma_f32_16x16x32_bf16(af, wf, acc[nt], 0, 0, 0);
            }
        }
    #pragma unroll
    for (int nt = 0; nt < 4; nt++) r1[nt] = acc[nt];
    __syncthreads();

    // ---- LN stats
    float v[4][4];
    #pragma unroll
    for (int nt = 0; nt < 4; nt++) {
        float bias0 = opb[n0w + nt * 16 + l15];
        #pragma unroll
        for (int r = 0; r < 4; r++)
            v[nt][r] = Xl[quad * 4 + r][n0w + nt * 16 + l15] + r0[nt][r] + bias0;
    }
    #pragma unroll
    for (int r = 0; r < 4; r++) {
        float s = v[0][r] + v[1][r] + v[2][r] + v[3][r];
        float s2 = v[0][r] * v[0][r] + v[1][r] * v[1][r] + v[2][r] * v[2][r] + v[3][r] * v[3][r];
        #pragma unroll
        for (int o = 1; o < 16; o <<= 1) { s += __shfl_xor(s, o); s2 += __shfl_xor(s2, o); }
        if (l15 == 0) { rsum[w][quad * 4 + r] = s; rsq[w][quad * 4 + r] = s2; }
    }
    __syncthreads();

    const float wgt = 1.f / (1.f + __expf(-alp[0]));
    float gv[4], bv[4], fb[4];
    #pragma unroll
    for (int nt = 0; nt < 4; nt++) {
        int n = n0w + nt * 16 + l15;
        gv[nt] = lng[n]; bv[nt] = lnb[n]; fb[nt] = fcb[n];
    }
    #pragma unroll
    for (int r = 0; r < 4; r++) {
        int row = quad * 4 + r;
        float S = rsum[0][row] + rsum[1][row] + rsum[2][row] + rsum[3][row];
        float S2 = rsq[0][row] + rsq[1][row] + rsq[2][row] + rsq[3][row];
        float mu = S * (1.f / CC);
        float var = S2 * (1.f / CC) - mu * mu;
        float rstd = rsqrtf(var + 1e-5f);
        #pragma unroll
        for (int nt = 0; nt < 4; nt++) {
            float ln = (v[nt][r] - mu) * rstd * gv[nt] + bv[nt];
            float cmb = wgt * r1[nt][r] + (1.f - wgt) * ln;
            Ab[row][n0w + nt * 16 + l15] = f2bf(cmb);
        }
    }
    __syncthreads();

    // ---- fc: out = comb @ fcw^T + fcb
    #pragma unroll
    for (int nt = 0; nt < 4; nt++) acc[nt] = z4;
    for (int kc = 0; kc < 4; kc++)
        #pragma unroll
        for (int c = 0; c < 2; c++) {
            bf16x8 af = *reinterpret_cast<const bf16x8*>(&Ab[l15][kc * 64 + c * 32 + quad * 8]);
            #pragma unroll
            for (int nt = 0; nt < 4; nt++) {
                bf16x8 wf = *reinterpret_cast<const bf16x8*>(
                    fcwb + (size_t)(n0w + nt * 16 + l15) * CC + kc * 64 + c * 32 + quad * 8);
                acc[nt] = __builtin_amdgcn_mfma_f32_16x16x32_bf16(af, wf, acc[nt], 0, 0, 0);
            }
        }
    #pragma unroll
    for (int nt = 0; nt < 4; nt++)
        #pragma unroll
        for (int r = 0; r < 4; r++)
            out[(size_t)(m0 + quad * 4 + r) * CC + n0w + nt * 16 + l15] = acc[nt][r] + fb[nt];
}

// ---------------------------------------------------------------- launch
extern "C" void kernel_launch(void* const* d_in, const int* in_sizes, int n_in,
                              void* d_out, int out_size, void* d_ws, size_t ws_size,
                              hipStream_t stream) {
    (void)in_sizes; (void)n_in; (void)out_size; (void)ws_size;
    const float* x    = (const float*)d_in[0];
    const int*   adj  = (const int*)d_in[1];
    const float* wloc = (const float*)d_in[2];
    const float* ipw  = (const float*)d_in[3];
    const float* ipb  = (const float*)d_in[4];
    const float* opw  = (const float*)d_in[5];
    const float* opb  = (const float*)d_in[6];
    const float* lng  = (const float*)d_in[7];
    const float* lnb  = (const float*)d_in[8];
    const float* alp  = (const float*)d_in[9];
    const float* fcw  = (const float*)d_in[10];
    const float* fcb  = (const float*)d_in[11];
    float* out = (float*)d_out;

    char* p = (char*)d_ws;
    int*   ideg   = (int*)p;    p += (size_t)NN * 4;
    int*   off    = (int*)p;    p += (size_t)(NN + 1) * 4;
    int*   cursor = (int*)p;    p += (size_t)NN * 4;
    float* rs     = (float*)p;  p += (size_t)NN * 4;
    int*   csr    = (int*)p;    p += (size_t)EE * 4;
    bf16* xb    = (bf16*)p;   p += (size_t)NN * CC * 2;
    bf16* hib   = (bf16*)p;   p += (size_t)NN * CC * 2;
    bf16* ipwb  = (bf16*)p;   p += (size_t)768 * 256 * 2;
    bf16* wlTb  = (bf16*)p;   p += (size_t)256 * 256 * 2;
    bf16* opwb  = (bf16*)p;   p += (size_t)256 * 256 * 2;
    bf16* fcwb  = (bf16*)p;   p += (size_t)256 * 256 * 2;
    bf16* qkvb  = (bf16*)p;   p += (size_t)NN * 768 * 2;
    bf16* Kpk   = (bf16*)p;   p += (size_t)HH * 512 * 2 * 512 * 2;
    bf16* Vpk   = (bf16*)p;   p += (size_t)HH * 256 * 4 * 512 * 2;
    bf16* aOb   = (bf16*)p;   p += (size_t)NN * CC * 2;
    float* Opf  = (float*)p;  p += (size_t)512 * 128 * 64 * 4;
    float* lpf  = (float*)p;  p += (size_t)512 * 128 * 4;

    hipMemsetAsync(ideg, 0, (size_t)NN * 4, stream);

    prep_all<<<4608, 256, 0, stream>>>(x, xb, ipw, opw, fcw, wloc, ipwb, opwb, fcwb, wlTb, adj, ideg);
    scan_offsets<<<1, 256, 0, stream>>>(ideg, off, cursor, rs);
    fill_csr<<<EE / 256, 256, 0, stream>>>(adj, cursor, csr);
    gcn_gather3<<<NN / 2, 256, 0, stream>>>(xb, csr, off, rs, hib);

    gemm_bt<<<dim3(NN / 128, 768 / 64), 256, 0, stream>>>(xb, ipwb, ipb, nullptr, qkvb, NN, 768, 256);
    build_kv<<<dim3(NN / 64, HH), 256, 0, stream>>>(qkvb, Kpk, Vpk);
    flash_attn17<<<512, 512, 0, stream>>>(qkvb, Kpk, Vpk, Opf, lpf);
    combine_attn<<<2048, 256, 0, stream>>>(Opf, lpf, aOb);
    gemm_ln_fc<<<NN / 16, 256, 0, stream>>>(aOb, opwb, opb, hib, wlTb, x, lng, lnb, alp, fcwb, fcb, out);
}

// Round 8
// 249.965 us; speedup vs baseline: 1.0549x; 1.0549x over previous
//
#include <hip/hip_runtime.h>
#include <hip/hip_bf16.h>
#include <math.h>

#define NN   8192
#define EE   262144
#define CC   256
#define HH   4

typedef __bf16 bf16;
typedef __bf16 bf16x8 __attribute__((ext_vector_type(8)));
typedef __bf16 bf16x4 __attribute__((ext_vector_type(4)));
typedef __bf16 bf16x2 __attribute__((ext_vector_type(2)));
typedef float  f32x4  __attribute__((ext_vector_type(4)));

static __device__ __forceinline__ bf16 f2bf(float f) { return (bf16)f; }

// packed f32x2 -> bf16x2 in one dword (v_cvt_pk_bf16_f32)
static __device__ __forceinline__ unsigned pk2(float a, float b) {
    __hip_bfloat162 h = __float22bfloat162_rn(float2{a, b});
    return *reinterpret_cast<unsigned*>(&h);
}

// ---------------------------------------------------------------- fused prep
__global__ void prep_all(const float* __restrict__ x, bf16* __restrict__ xb,
                         const float* __restrict__ ipw, const float* __restrict__ opw,
                         const float* __restrict__ fcw, const float* __restrict__ wloc,
                         bf16* __restrict__ ipwb, bf16* __restrict__ opwb,
                         bf16* __restrict__ fcwb, bf16* __restrict__ wlTb,
                         const int* __restrict__ adj, int* __restrict__ ideg) {
    int b = blockIdx.x, t = threadIdx.x;
    if (b < 2048) {
        for (int i = b * 256 + t; i < NN * CC; i += 2048 * 256) xb[i] = f2bf(x[i]);
    } else if (b < 2816) { int i = (b - 2048) * 256 + t; ipwb[i] = f2bf(ipw[i]); }
    else if (b < 3072)   { int i = (b - 2816) * 256 + t; opwb[i] = f2bf(opw[i]); }
    else if (b < 3328)   { int i = (b - 3072) * 256 + t; fcwb[i] = f2bf(fcw[i]); }
    else if (b < 3584)   { int n = b - 3328;             wlTb[n * 256 + t] = f2bf(wloc[t * 256 + n]); }
    else {
        int e = (b - 3584) * 256 + t;
        if (e < EE) atomicAdd(&ideg[adj[EE + e]], 1);
    }
}

// ---------------------------------------------------------------- K/V fragment prepack (fused)
__global__ __launch_bounds__(256) void build_kv(const bf16* __restrict__ qkv,
                                                bf16* __restrict__ Kpk,
                                                bf16* __restrict__ Vpk) {
    __shared__ bf16 tl[64][72];
    const int bx = blockIdx.x;     // 64-key tile
    const int h  = blockIdx.y;
    const int tid = threadIdx.x;
    // ---- K
    #pragma unroll
    for (int i = 0; i < 2; i++) {
        int u = tid + i * 256;
        int key = u >> 3, g = u & 7;
        *reinterpret_cast<bf16x8*>(&tl[key][g * 8]) =
            *reinterpret_cast<const bf16x8*>(qkv + (size_t)(bx * 64 + key) * 768 + 256 + h * 64 + g * 8);
    }
    __syncthreads();
    #pragma unroll
    for (int i = 0; i < 2; i++) {
        int ee = tid + i * 256;
        int l15 = ee & 15, quad = (ee >> 4) & 3, c = (ee >> 6) & 1, ktl = ee >> 7;
        int key_local = (ktl >> 1) * 32 + (l15 >> 2) * 8 + (ktl & 1) * 4 + (l15 & 3);
        bf16x8 v = *reinterpret_cast<const bf16x8*>(&tl[key_local][c * 32 + quad * 8]);
        *reinterpret_cast<bf16x8*>(Kpk + ((size_t)((h * 512 + bx * 4 + ktl) * 2 + c)) * 512
                                       + (quad * 16 + l15) * 8) = v;
    }
    __syncthreads();
    // ---- V
    #pragma unroll
    for (int i = 0; i < 2; i++) {
        int u = tid + i * 256;
        int key = u >> 3, g = u & 7;
        *reinterpret_cast<bf16x8*>(&tl[key][g * 8]) =
            *reinterpret_cast<const bf16x8*>(qkv + (size_t)(bx * 64 + key) * 768 + 512 + h * 64 + g * 8);
    }
    __syncthreads();
    #pragma unroll
    for (int i = 0; i < 2; i++) {
        int ee = tid + i * 256;
        int l15 = ee & 15, quad = (ee >> 4) & 3, nt = (ee >> 6) & 3, kcl = ee >> 8;
        bf16x8 v;
        #pragma unroll
        for (int j = 0; j < 8; j++) v[j] = tl[kcl * 32 + quad * 8 + j][nt * 16 + l15];
        *reinterpret_cast<bf16x8*>(Vpk + ((size_t)((h * 256 + bx * 2 + kcl) * 4 + nt)) * 512
                                       + (quad * 16 + l15) * 8) = v;
    }
}

// ---------------------------------------------------------------- GCN CSR build
__global__ __launch_bounds__(256) void scan_offsets(const int* __restrict__ ideg,
        int* __restrict__ off, int* __restrict__ cursor, float* __restrict__ rs) {
    __shared__ int ps[256];
    const int tid = threadIdx.x;
    const int base = tid * 32;
    int loc[32];
    int s = 0;
    #pragma unroll
    for (int i = 0; i < 32; i++) { loc[i] = s; s += ideg[base + i]; }
    ps[tid] = s;
    __syncthreads();
    for (int d = 1; d < 256; d <<= 1) {
        int v = (tid >= d) ? ps[tid - d] : 0;
        __syncthreads();
        ps[tid] += v;
        __syncthreads();
    }
    int excl = ps[tid] - s;
    #pragma unroll
    for (int i = 0; i < 32; i++) {
        int o = excl + loc[i];
        off[base + i] = o;
        cursor[base + i] = o;
        int dg = ideg[base + i];
        rs[base + i] = dg > 0 ? rsqrtf((float)dg) : 0.f;
    }
    if (tid == 255) off[8192] = excl + s;
}

__global__ void fill_csr(const int* __restrict__ adj, int* __restrict__ cursor,
                         int* __restrict__ csr) {
    int e = blockIdx.x * 256 + threadIdx.x;
    if (e < EE) {
        int col = adj[EE + e];
        int pos = atomicAdd(&cursor[col], 1);
        csr[pos] = adj[e];
    }
}

// ---------------------------------------------------------------- GCN gather v3
__global__ __launch_bounds__(256) void gcn_gather3(const bf16* __restrict__ xb,
        const int* __restrict__ csr, const int* __restrict__ off,
        const float* __restrict__ rs, bf16* __restrict__ hib) {
    const int node = blockIdx.x * 2 + (threadIdx.x >> 7);
    const int j = threadIdx.x & 127;
    const int o = off[node];
    const int cnt = off[node + 1] - o;
    const float rsc = rs[node];
    const unsigned* xrow = (const unsigned*)xb;
    float a0 = 0.f, a1 = 0.f;
    int e = 0;
    for (; e + 8 <= cnt; e += 8) {
        int r[8];
        float v[8];
        unsigned u[8];
        #pragma unroll
        for (int i = 0; i < 8; i++) r[i] = csr[o + e + i];
        #pragma unroll
        for (int i = 0; i < 8; i++) v[i] = rsc * rs[r[i]];
        #pragma unroll
        for (int i = 0; i < 8; i++) u[i] = xrow[(size_t)r[i] * 128 + j];
        #pragma unroll
        for (int i = 0; i < 8; i++) {
            a0 += __uint_as_float(u[i] << 16) * v[i];
            a1 += __uint_as_float(u[i] & 0xffff0000u) * v[i];
        }
    }
    for (; e < cnt; e++) {
        int r0 = csr[o + e];
        float v0 = rsc * rs[r0];
        unsigned u0 = xrow[(size_t)r0 * 128 + j];
        a0 += __uint_as_float(u0 << 16) * v0;
        a1 += __uint_as_float(u0 & 0xffff0000u) * v0;
    }
    bf16x2 pk;
    pk[0] = f2bf(a0);
    pk[1] = f2bf(a1);
    ((bf16x2*)(hib + (size_t)node * CC))[j] = pk;
}

// ---------------------------------------------------------------- BT GEMM (qkv)
__global__ __launch_bounds__(256) void gemm_bt(
        const bf16* __restrict__ A, const bf16* __restrict__ W,
        const float* __restrict__ bias,
        float* __restrict__ outF, bf16* __restrict__ outB,
        int M, int N, int K) {
    const int tid  = threadIdx.x;
    const int wave = tid >> 6;
    const int lane = tid & 63;
    const int quad = lane >> 4;
    const int l15  = lane & 15;
    const int m0 = blockIdx.x * 128;
    const int n0 = blockIdx.y * 64;

    __shared__ bf16 Alds[128][72];
    __shared__ bf16 Wlds[64][72];

    f32x4 acc[2][4];
    #pragma unroll
    for (int mt = 0; mt < 2; mt++)
        #pragma unroll
        for (int nt = 0; nt < 4; nt++)
            acc[mt][nt] = (f32x4){0.f, 0.f, 0.f, 0.f};

    for (int k0 = 0; k0 < K; k0 += 64) {
        #pragma unroll
        for (int i = 0; i < 4; i++) {
            int u = tid + i * 256;
            int r = u >> 3;
            int cp = u & 7;
            *reinterpret_cast<bf16x8*>(&Alds[r][cp * 8]) =
                *reinterpret_cast<const bf16x8*>(A + (size_t)(m0 + r) * K + k0 + cp * 8);
        }
        #pragma unroll
        for (int i = 0; i < 2; i++) {
            int u = tid + i * 256;
            int r = u >> 3;
            int cp = u & 7;
            *reinterpret_cast<bf16x8*>(&Wlds[r][cp * 8]) =
                *reinterpret_cast<const bf16x8*>(W + (size_t)(n0 + r) * K + k0 + cp * 8);
        }
        __syncthreads();
        #pragma unroll
        for (int c = 0; c < 2; c++) {
            bf16x8 af[2], wf[4];
            #pragma unroll
            for (int mt = 0; mt < 2; mt++)
                af[mt] = *reinterpret_cast<const bf16x8*>(&Alds[wave * 32 + mt * 16 + l15][c * 32 + quad * 8]);
            #pragma unroll
            for (int nt = 0; nt < 4; nt++)
                wf[nt] = *reinterpret_cast<const bf16x8*>(&Wlds[nt * 16 + l15][c * 32 + quad * 8]);
            #pragma unroll
            for (int mt = 0; mt < 2; mt++)
                #pragma unroll
                for (int nt = 0; nt < 4; nt++)
                    acc[mt][nt] = __builtin_amdgcn_mfma_f32_16x16x32_bf16(af[mt], wf[nt], acc[mt][nt], 0, 0, 0);
        }
        __syncthreads();
    }
    #pragma unroll
    for (int mt = 0; mt < 2; mt++)
        #pragma unroll
        for (int nt = 0; nt < 4; nt++)
            #pragma unroll
            for (int r = 0; r < 4; r++) {
                int m = m0 + wave * 32 + mt * 16 + quad * 4 + r;
                int n = n0 + nt * 16 + l15;
                float v = acc[mt][nt][r];
                if (bias) v += bias[n];
                if (outF) outF[(size_t)m * N + n] = v;
                else      outB[(size_t)m * N + n] = f2bf(v);
            }
}

// ---------------------------------------------------------------- flash attention v18
// v15 verbatim + ONE line: anti-phase stagger. Evidence (v10/15/16/17):
// elapsed = MFMA_busy + VALU_busy (97% sum, ~0 overlap). The 2 waves/SIMD
// (w and w+4 of the same block: same SIMD, differ in g) start the same
// cycle, run identical code with identical latencies -> phase-locked: both
// burst MFMAs together (matrix pipe serializes), both burst exps together
// (trans pipe serializes). Anti-phase is a stable equilibrium (no
// contention -> both run free -> offset persists); it just needs an
// initial kick: g=1 waves s_sleep ~704 cyc (~half the measured ~1460-cyc
// per-chunk period) before the main loop. Occupancy can't rise instead:
// VGPR 108 + 80 AGPR (oacc+lacc) = ~188 regs/wave caps at 2 waves/SIMD.
__global__ __launch_bounds__(512, 2) void flash_attn18(const bf16* __restrict__ qkv,
                                                       const bf16* __restrict__ Kpk,
                                                       const bf16* __restrict__ Vpk,
                                                       bf16* __restrict__ attnO) {
    const int tid  = threadIdx.x;
    const int w    = tid >> 6;           // 0..7
    const int g    = w >> 2;             // q-group
    const int k4   = w & 3;              // key-split lane within group
    const int lane = tid & 63;
    const int quad = lane >> 4;
    const int l15  = lane & 15;
    const int bx = blockIdx.x;
    const int h  = (bx & 7) >> 1;        // XCD affinity (neutral, kept)
    const int qb = (bx >> 3) * 2 + (bx & 1);   // 0..63, bijective with h
    const int qbase = qb * 128 + g * 64;

    __shared__ bf16 Osh[8][64][68];
    __shared__ float lsh[8][64];

    const float qs = 0.180336880f;
    bf16x8 qf[4][2];
    #pragma unroll
    for (int qt = 0; qt < 4; qt++)
        #pragma unroll
        for (int c = 0; c < 2; c++) {
            bf16x8 raw = *reinterpret_cast<const bf16x8*>(
                qkv + (size_t)(qbase + qt * 16 + l15) * 768 + h * 64 + c * 32 + quad * 8);
            #pragma unroll
            for (int j = 0; j < 8; j++) qf[qt][c][j] = f2bf((float)raw[j] * qs);
        }

    const bf16* Kb = Kpk + (size_t)h * 524288 + lane * 8;
    const bf16* Vb = Vpk + (size_t)h * 524288 + lane * 8;

    f32x4 oacc[4][4];
    #pragma unroll
    for (int qt = 0; qt < 4; qt++)
        #pragma unroll
        for (int nt = 0; nt < 4; nt++) oacc[qt][nt] = (f32x4){0.f, 0.f, 0.f, 0.f};
    f32x4 lacc[4];
    #pragma unroll
    for (int qt = 0; qt < 4; qt++) lacc[qt] = (f32x4){0.f, 0.f, 0.f, 0.f};
    bf16x8 onesf;
    #pragma unroll
    for (int j = 0; j < 8; j++) onesf[j] = f2bf(1.0f);
    const f32x4 z4 = (f32x4){0.f, 0.f, 0.f, 0.f};

    bf16x8 kfA[2][2], vfA[4], kfB[2][2], vfB[4];

    #define LOADKV(kc, kf, vf)                                                          \
        {                                                                               \
            _Pragma("unroll")                                                           \
            for (int s = 0; s < 2; s++)                                                 \
                _Pragma("unroll")                                                       \
                for (int c = 0; c < 2; c++)                                             \
                    kf[s][c] = *reinterpret_cast<const bf16x8*>(Kb + (kc) * 2048 + s * 1024 + c * 512); \
            _Pragma("unroll")                                                           \
            for (int nt = 0; nt < 4; nt++)                                              \
                vf[nt] = *reinterpret_cast<const bf16x8*>(Vb + (kc) * 2048 + nt * 512); \
        }

    #define COMPUTE(kf, vf)                                                             \
        {                                                                               \
            f32x4 sacc[2][4];                                                           \
            __builtin_amdgcn_s_setprio(1);                                              \
            _Pragma("unroll")                                                           \
            for (int s = 0; s < 2; s++)                                                 \
                _Pragma("unroll")                                                       \
                for (int qt = 0; qt < 4; qt++) {                                        \
                    sacc[s][qt] = __builtin_amdgcn_mfma_f32_16x16x32_bf16(kf[s][0], qf[qt][0], z4, 0, 0, 0); \
                    sacc[s][qt] = __builtin_amdgcn_mfma_f32_16x16x32_bf16(kf[s][1], qf[qt][1], sacc[s][qt], 0, 0, 0); \
                }                                                                       \
            __builtin_amdgcn_s_setprio(0);                                              \
            _Pragma("unroll")                                                           \
            for (int qt = 0; qt < 4; qt++) {                                            \
                float e0 = __builtin_amdgcn_exp2f(sacc[0][qt][0]);                      \
                float e1 = __builtin_amdgcn_exp2f(sacc[0][qt][1]);                      \
                float e2 = __builtin_amdgcn_exp2f(sacc[0][qt][2]);                      \
                float e3 = __builtin_amdgcn_exp2f(sacc[0][qt][3]);                      \
                float e4 = __builtin_amdgcn_exp2f(sacc[1][qt][0]);                      \
                float e5 = __builtin_amdgcn_exp2f(sacc[1][qt][1]);                      \
                float e6 = __builtin_amdgcn_exp2f(sacc[1][qt][2]);                      \
                float e7 = __builtin_amdgcn_exp2f(sacc[1][qt][3]);                      \
                union { bf16x8 v; unsigned u[4]; } pu;                                  \
                pu.u[0] = pk2(e0, e1);                                                  \
                pu.u[1] = pk2(e2, e3);                                                  \
                pu.u[2] = pk2(e4, e5);                                                  \
                pu.u[3] = pk2(e6, e7);                                                  \
                __builtin_amdgcn_s_setprio(1);                                          \
                _Pragma("unroll")                                                       \
                for (int nt = 0; nt < 4; nt++)                                          \
                    oacc[qt][nt] = __builtin_amdgcn_mfma_f32_16x16x32_bf16(pu.v, vf[nt], oacc[qt][nt], 0, 0, 0); \
                lacc[qt] = __builtin_amdgcn_mfma_f32_16x16x32_bf16(pu.v, onesf, lacc[qt], 0, 0, 0); \
                __builtin_amdgcn_s_setprio(0);                                          \
            }                                                                           \
        }

    // anti-phase kick: g=1 waves (co-resident on the same SIMD as their
    // g=0 partner) delay ~704 cycles = half the per-chunk period.
    if (g == 1) __builtin_amdgcn_s_sleep(11);

    LOADKV(k4, kfA, vfA);
    for (int it = 0; it < 64; it += 2) {
        const int kB = k4 + (it + 1) * 4;
        LOADKV(kB, kfB, vfB);
        COMPUTE(kfA, vfA);
        int kA2 = k4 + (it + 2) * 4;
        if (kA2 > 255) kA2 = k4;
        LOADKV(kA2, kfA, vfA);
        COMPUTE(kfB, vfB);
    }
    #undef LOADKV
    #undef COMPUTE

    #pragma unroll
    for (int qt = 0; qt < 4; qt++)
        #pragma unroll
        for (int nt = 0; nt < 4; nt++)
            #pragma unroll
            for (int r = 0; r < 4; r++)
                Osh[w][qt * 16 + quad * 4 + r][nt * 16 + l15] = f2bf(oacc[qt][nt][r]);
    if (l15 == 0) {
        #pragma unroll
        for (int qt = 0; qt < 4; qt++)
            #pragma unroll
            for (int r = 0; r < 4; r++)
                lsh[w][qt * 16 + quad * 4 + r] = lacc[qt][r];
    }
    __syncthreads();

    const int q7 = tid >> 2;             // 0..127
    const int gg = q7 >> 6;
    const int ql = q7 & 63;
    const int ds = (tid & 3) * 16;
    const int wb = gg * 4;
    float lsum = lsh[wb][ql] + lsh[wb + 1][ql] + lsh[wb + 2][ql] + lsh[wb + 3][ql];
    float linv = 1.f / lsum;
    float acc[16];
    #pragma unroll
    for (int i = 0; i < 16; i++) acc[i] = 0.f;
    #pragma unroll
    for (int v = 0; v < 4; v++) {
        bf16x8 o0 = *reinterpret_cast<const bf16x8*>(&Osh[wb + v][ql][ds]);
        bf16x8 o1 = *reinterpret_cast<const bf16x8*>(&Osh[wb + v][ql][ds + 8]);
        #pragma unroll
        for (int i = 0; i < 8; i++) { acc[i] += (float)o0[i]; acc[8 + i] += (float)o1[i]; }
    }
    bf16x8 ob0, ob1;
    #pragma unroll
    for (int i = 0; i < 8; i++) {
        ob0[i] = f2bf(acc[i] * linv);
        ob1[i] = f2bf(acc[8 + i] * linv);
    }
    bf16* dst = attnO + (size_t)(qb * 128 + q7) * CC + h * 64 + ds;
    *reinterpret_cast<bf16x8*>(dst) = ob0;
    *reinterpret_cast<bf16x8*>(dst + 8) = ob1;
}

// ---------------------------------------------------------------- gemm + LN + combine + fc
__global__ __launch_bounds__(256) void gemm_ln_fc(
        const bf16* __restrict__ aOb, const bf16* __restrict__ opwb, const float* __restrict__ opb,
        const bf16* __restrict__ hib, const bf16* __restrict__ wlTb,
        const float* __restrict__ x, const float* __restrict__ lng, const float* __restrict__ lnb,
        const float* __restrict__ alp, const bf16* __restrict__ fcwb, const float* __restrict__ fcb,
        float* __restrict__ out) {
    const int tid = threadIdx.x;
    const int w = tid >> 6, lane = tid & 63, quad = lane >> 4, l15 = lane & 15;
    const int m0 = blockIdx.x * 16;
    const int n0w = w * 64;
    const f32x4 z4 = (f32x4){0.f, 0.f, 0.f, 0.f};

    __shared__ bf16 Ab[16][264];
    __shared__ float Xl[16][260];
    __shared__ float rsum[4][16], rsq[4][16];

    #pragma unroll
    for (int i = 0; i < 4; i++) {
        int u = tid + i * 256;
        int row = u >> 6, cp = (u & 63) * 4;
        *reinterpret_cast<f32x4*>(&Xl[row][cp]) =
            *reinterpret_cast<const f32x4*>(x + (size_t)(m0 + row) * CC + cp);
    }

    // ---- gemm0: aprj tile (A = aOb)
    #pragma unroll
    for (int i = 0; i < 2; i++) {
        int u = tid + i * 256;
        int row = u >> 5, cp = (u & 31) * 8;
        *reinterpret_cast<bf16x8*>(&Ab[row][cp]) =
            *reinterpret_cast<const bf16x8*>(aOb + (size_t)(m0 + row) * CC + cp);
    }
    __syncthreads();
    f32x4 r0[4], r1[4], acc[4];
    #pragma unroll
    for (int nt = 0; nt < 4; nt++) acc[nt] = z4;
    for (int kc = 0; kc < 4; kc++)
        #pragma unroll
        for (int c = 0; c < 2; c++) {
            bf16x8 af = *reinterpret_cast<const bf16x8*>(&Ab[l15][kc * 64 + c * 32 + quad * 8]);
            #pragma unroll
            for (int nt = 0; nt < 4; nt++) {
                bf16x8 wf = *reinterpret_cast<const bf16x8*>(
                    opwb + (size_t)(n0w + nt * 16 + l15) * CC + kc * 64 + c * 32 + quad * 8);
                acc[nt] = __builtin_amdgcn_mfma_f32_16x16x32_bf16(af, wf, acc[nt], 0, 0, 0);
            }
        }
    #pragma unroll
    for (int nt = 0; nt < 4; nt++) r0[nt] = acc[nt];
    __syncthreads();

    // ---- gemm1: locl tile (A = hib)
    #pragma unroll
    for (int i = 0; i < 2; i++) {
        int u = tid + i * 256;
        int row = u >> 5, cp = (u & 31) * 8;
        *reinterpret_cast<bf16x8*>(&Ab[row][cp]) =
            *reinterpret_cast<const bf16x8*>(hib + (size_t)(m0 + row) * CC + cp);
    }
    __syncthreads();
    #pragma unroll
    for (int nt = 0; nt < 4; nt++) acc[nt] = z4;
    for (int kc = 0; kc < 4; kc++)
        #pragma unroll
        for (int c = 0; c < 2; c++) {
            bf16x8 af = *reinterpret_cast<const bf16x8*>(&Ab[l15][kc * 64 + c * 32 + quad * 8]);
            #pragma unroll
            for (int nt = 0; nt < 4; nt++) {
                bf16x8 wf = *reinterpret_cast<const bf16x8*>(
                    wlTb + (size_t)(n0w + nt * 16 + l15) * CC + kc * 64 + c * 32 + quad * 8);
                acc[nt] = __builtin_amdgcn_mfma_f32_16x16x32_bf16(af, wf, acc[nt], 0, 0, 0);
            }
        }
    #pragma unroll
    for (int nt = 0; nt < 4; nt++) r1[nt] = acc[nt];
    __syncthreads();

    // ---- LN stats
    float v[4][4];
    #pragma unroll
    for (int nt = 0; nt < 4; nt++) {
        float bias0 = opb[n0w + nt * 16 + l15];
        #pragma unroll
        for (int r = 0; r < 4; r++)
            v[nt][r] = Xl[quad * 4 + r][n0w + nt * 16 + l15] + r0[nt][r] + bias0;
    }
    #pragma unroll
    for (int r = 0; r < 4; r++) {
        float s = v[0][r] + v[1][r] + v[2][r] + v[3][r];
        float s2 = v[0][r] * v[0][r] + v[1][r] * v[1][r] + v[2][r] * v[2][r] + v[3][r] * v[3][r];
        #pragma unroll
        for (int o = 1; o < 16; o <<= 1) { s += __shfl_xor(s, o); s2 += __shfl_xor(s2, o); }
        if (l15 == 0) { rsum[w][quad * 4 + r] = s; rsq[w][quad * 4 + r] = s2; }
    }
    __syncthreads();

    const float wgt = 1.f / (1.f + __expf(-alp[0]));
    float gv[4], bv[4], fb[4];
    #pragma unroll
    for (int nt = 0; nt < 4; nt++) {
        int n = n0w + nt * 16 + l15;
        gv[nt] = lng[n]; bv[nt] = lnb[n]; fb[nt] = fcb[n];
    }
    #pragma unroll
    for (int r = 0; r < 4; r++) {
        int row = quad * 4 + r;
        float S = rsum[0][row] + rsum[1][row] + rsum[2][row] + rsum[3][row];
        float S2 = rsq[0][row] + rsq[1][row] + rsq[2][row] + rsq[3][row];
        float mu = S * (1.f / CC);
        float var = S2 * (1.f / CC) - mu * mu;
        float rstd = rsqrtf(var + 1e-5f);
        #pragma unroll
        for (int nt = 0; nt < 4; nt++) {
            float ln = (v[nt][r] - mu) * rstd * gv[nt] + bv[nt];
            float cmb = wgt * r1[nt][r] + (1.f - wgt) * ln;
            Ab[row][n0w + nt * 16 + l15] = f2bf(cmb);
        }
    }
    __syncthreads();

    // ---- fc: out = comb @ fcw^T + fcb
    #pragma unroll
    for (int nt = 0; nt < 4; nt++) acc[nt] = z4;
    for (int kc = 0; kc < 4; kc++)
        #pragma unroll
        for (int c = 0; c < 2; c++) {
            bf16x8 af = *reinterpret_cast<const bf16x8*>(&Ab[l15][kc * 64 + c * 32 + quad * 8]);
            #pragma unroll
            for (int nt = 0; nt < 4; nt++) {
                bf16x8 wf = *reinterpret_cast<const bf16x8*>(
                    fcwb + (size_t)(n0w + nt * 16 + l15) * CC + kc * 64 + c * 32 + quad * 8);
                acc[nt] = __builtin_amdgcn_mfma_f32_16x16x32_bf16(af, wf, acc[nt], 0, 0, 0);
            }
        }
    #pragma unroll
    for (int nt = 0; nt < 4; nt++)
        #pragma unroll
        for (int r = 0; r < 4; r++)
            out[(size_t)(m0 + quad * 4 + r) * CC + n0w + nt * 16 + l15] = acc[nt][r] + fb[nt];
}

// ---------------------------------------------------------------- launch
extern "C" void kernel_launch(void* const* d_in, const int* in_sizes, int n_in,
                              void* d_out, int out_size, void* d_ws, size_t ws_size,
                              hipStream_t stream) {
    (void)in_sizes; (void)n_in; (void)out_size; (void)ws_size;
    const float* x    = (const float*)d_in[0];
    const int*   adj  = (const int*)d_in[1];
    const float* wloc = (const float*)d_in[2];
    const float* ipw  = (const float*)d_in[3];
    const float* ipb  = (const float*)d_in[4];
    const float* opw  = (const float*)d_in[5];
    const float* opb  = (const float*)d_in[6];
    const float* lng  = (const float*)d_in[7];
    const float* lnb  = (const float*)d_in[8];
    const float* alp  = (const float*)d_in[9];
    const float* fcw  = (const float*)d_in[10];
    const float* fcb  = (const float*)d_in[11];
    float* out = (float*)d_out;

    char* p = (char*)d_ws;
    int*   ideg   = (int*)p;    p += (size_t)NN * 4;
    int*   off    = (int*)p;    p += (size_t)(NN + 1) * 4;
    int*   cursor = (int*)p;    p += (size_t)NN * 4;
    float* rs     = (float*)p;  p += (size_t)NN * 4;
    int*   csr    = (int*)p;    p += (size_t)EE * 4;
    bf16* xb    = (bf16*)p;   p += (size_t)NN * CC * 2;
    bf16* hib   = (bf16*)p;   p += (size_t)NN * CC * 2;
    bf16* ipwb  = (bf16*)p;   p += (size_t)768 * 256 * 2;
    bf16* wlTb  = (bf16*)p;   p += (size_t)256 * 256 * 2;
    bf16* opwb  = (bf16*)p;   p += (size_t)256 * 256 * 2;
    bf16* fcwb  = (bf16*)p;   p += (size_t)256 * 256 * 2;
    bf16* qkvb  = (bf16*)p;   p += (size_t)NN * 768 * 2;
    bf16* Kpk   = (bf16*)p;   p += (size_t)HH * 512 * 2 * 512 * 2;
    bf16* Vpk   = (bf16*)p;   p += (size_t)HH * 256 * 4 * 512 * 2;
    bf16* aOb   = (bf16*)p;   p += (size_t)NN * CC * 2;

    hipMemsetAsync(ideg, 0, (size_t)NN * 4, stream);

    prep_all<<<4608, 256, 0, stream>>>(x, xb, ipw, opw, fcw, wloc, ipwb, opwb, fcwb, wlTb, adj, ideg);
    scan_offsets<<<1, 256, 0, stream>>>(ideg, off, cursor, rs);
    fill_csr<<<EE / 256, 256, 0, stream>>>(adj, cursor, csr);
    gcn_gather3<<<NN / 2, 256, 0, stream>>>(xb, csr, off, rs, hib);

    gemm_bt<<<dim3(NN / 128, 768 / 64), 256, 0, stream>>>(xb, ipwb, ipb, nullptr, qkvb, NN, 768, 256);
    build_kv<<<dim3(NN / 64, HH), 256, 0, stream>>>(qkvb, Kpk, Vpk);
    flash_attn18<<<256, 512, 0, stream>>>(qkvb, Kpk, Vpk, aOb);
    gemm_ln_fc<<<NN / 16, 256, 0, stream>>>(aOb, opwb, opb, hib, wlTb, x, lng, lnb, alp, fcwb, fcb, out);
}